// Round 1
// 375.583 us; speedup vs baseline: 1.0091x; 1.0091x over previous
//
#include <hip/hip_runtime.h>
#include <cstdint>
#include <cfloat>

// Problem constants (B=64, H=12, P=197, D=64)
#define NK 10
constexpr int Pp   = 197;
constexpr int Dd   = 64;
constexpr int ROWS = 64 * 12 * 197;      // 151296
constexpr int BLK  = 128;                // 2 independent waves per block
constexpr int WPB  = BLK / 64;           // 2 waves/block
constexpr int RPW  = 64;                 // rows per wave
constexpr int RPB  = RPW * WPB;          // 128 rows per block
constexpr int NBLK = ROWS / RPB;         // 1182 (exact)
constexpr int CH   = 32;                 // staging chunk width (cols)
constexpr int NFULL = Pp / CH;           // 6
constexpr int TAIL  = Pp - NFULL * CH;   // 5
constexpr float INV_N = 1.0f / 9682944.0f;   // 1/(ROWS*D)

constexpr int RPB_B = 16;                // rows per gather block (16 waves)
constexpr int NB_B  = ROWS / RPB_B;      // 9456 (exact)

__device__ __forceinline__ uint32_t fbits(float x) { return __float_as_uint(x); }
__device__ __forceinline__ float    bfl(uint32_t u) { return __uint_as_float(u); }

// Branchless sorted-insert into ascending a[0..9].
template <int CW>
__device__ __forceinline__ void consume_chunk(const float* __restrict__ trow,
                                              float a[NK]) {
#pragma unroll
  for (int j = 0; j < CW; ++j) {
    float x = trow[j];
#pragma unroll
    for (int s = 0; s < NK - 1; ++s) a[s] = fmaxf(a[s], fminf(x, a[s + 1]));
    a[NK - 1] = fmaxf(a[NK - 1], x);
  }
}

// Per-wave: load chunk c of this wave's 64-row slab into registers, packing
// the column index into the low 8 mantissa bits (rel. perturbation 2^-16).
// Full chunks: lane l = r0*32+j (r0 in {0,1}), loads rows r0+2i, col c*32+j.
// Each half-wave issues a 128B-contiguous segment per instruction.
__device__ __forceinline__ void load_chunk_regs(const float* __restrict__ slab,
                                                int c, int l, float pf[CH]) {
  if (c < NFULL) {
    const int r0 = l >> 5, j = l & 31;
    const uint32_t col = (uint32_t)(c * CH + j);
    const float* p = slab + c * CH + r0 * Pp + j;
#pragma unroll
    for (int i = 0; i < CH; ++i) {
      float x = __builtin_nontemporal_load(&p[i * 2 * Pp]);  // att is read-once
      pf[i] = bfl((fbits(x) & 0xFFFFFF00u) | col);
    }
  } else {
    const float* cbase = slab + NFULL * CH;
#pragma unroll
    for (int i = 0; i < TAIL; ++i) {
      int e = l + i * 64;                  // 0..319 over 64 rows x 5 cols
      int r = e / TAIL, j = e % TAIL;
      float x = __builtin_nontemporal_load(&cbase[r * Pp + j]);
      pf[i] = bfl((fbits(x) & 0xFFFFFF00u) | (uint32_t)(NFULL * CH + j));
    }
  }
}

// Per-wave store into this wave's private [64][33] tile (stride 33 floats:
// bank = (row + col) % 32 -> 2 lanes/bank on wave64 b32 = conflict-free).
__device__ __forceinline__ void store_chunk(float (*twv)[CH + 1], int c, int l,
                                            const float pf[CH]) {
  if (c < NFULL) {
    const int r0 = l >> 5, j = l & 31;
#pragma unroll
    for (int i = 0; i < CH; ++i) twv[r0 + 2 * i][j] = pf[i];
  } else {
#pragma unroll
    for (int i = 0; i < TAIL; ++i) {
      int e = l + i * 64;
      twv[e / TAIL][e % TAIL] = pf[i];
    }
  }
}

// Kernel A: wave-autonomous selection. Each wave owns 64 rows of ONE tensor
// and a private LDS tile -> ZERO __syncthreads. Register-prefetched chunk
// pipeline: store(c) -> issue loads(c+1) -> consume(c). Same-wave DS ordering
// guarantees store->consume correctness without barriers.
__global__ __launch_bounds__(BLK, 4) void select_kernel(
    const float* __restrict__ att_s, const float* __restrict__ att_t,
    float* __restrict__ wpk /* [2][ROWS][NK] */) {
  __shared__ float tile[WPB][RPW][CH + 1];  // 2*64*33*4 = 16896 B

  const int t = threadIdx.x;
  const int wv = t >> 6, l = t & 63;
  const int bi = blockIdx.x;
  const int tensor = (bi >= NBLK) ? 1 : 0;
  const int slab = bi - tensor * NBLK;
  const float* A = tensor ? att_t : att_s;
  const int rowbase = slab * RPB + wv * RPW;

  float a[NK];
#pragma unroll
  for (int k = 0; k < NK; ++k) a[k] = -FLT_MAX;

  const float* slabp = A + (size_t)rowbase * Pp;
  float (*twv)[CH + 1] = tile[wv];
  float pf[CH];

  load_chunk_regs(slabp, 0, l, pf);
  for (int c = 0; c <= NFULL; ++c) {
    store_chunk(twv, c, l, pf);            // waits on chunk-c loads only
    if (c < NFULL) {
      load_chunk_regs(slabp, c + 1, l, pf);  // next chunk in flight
      consume_chunk<CH>(twv[l], a);          // hides the load latency
    } else {
      consume_chunk<TAIL>(twv[l], a);
    }
  }

  // softmax over the top-10 (full-row Z cancels against the renorm)
  float mx = a[NK - 1];
  float e[NK], s = 0.f;
#pragma unroll
  for (int k = 0; k < NK; ++k) { e[k] = __expf(a[k] - mx); s += e[k]; }
  float inv = 1.0f / s;

  // stage packed weights in the (now free) wave tile, then coalesced store
  float* flat = &twv[0][0];                 // 2112 floats >= 640 needed
#pragma unroll
  for (int k = 0; k < NK; ++k) {
    float w = e[k] * inv;  // w >= ~1e-6 -> normal, mantissa packing safe
    flat[l * NK + k] = bfl((fbits(w) & 0xFFFFFF00u) | (fbits(a[k]) & 0xFFu));
  }
  float* dst = wpk + ((size_t)tensor * ROWS + rowbase) * NK;
#pragma unroll
  for (int i = 0; i < NK; ++i) dst[l + i * 64] = flat[l + i * 64];
}

// Kernel B: wave-per-row gather + squared-diff partial per block.
__global__ __launch_bounds__(1024) void gather_kernel(
    const float* __restrict__ v_s, const float* __restrict__ v_t,
    const float* __restrict__ wpk, float* __restrict__ partial) {
  const int t = threadIdx.x, wv = t >> 6, l = t & 63;
  int row = blockIdx.x * RPB_B + wv;
  row = __builtin_amdgcn_readfirstlane(row);  // force SGPR: scalar w loads
  const int bh = row / Pp;
  const float* vsb = v_s + (size_t)bh * (Pp * Dd) + l;
  const float* vtb = v_t + (size_t)bh * (Pp * Dd) + l;
  const float* w0 = wpk + (size_t)row * NK;
  const float* w1 = wpk + ((size_t)ROWS + row) * NK;

  float acc = 0.f;
#pragma unroll
  for (int k = 0; k < NK; ++k) {
    float w = w0[k];
    int idx = (int)(fbits(w) & 0xFFu);
    acc = fmaf(w, vsb[idx * Dd], acc);
  }
#pragma unroll
  for (int k = 0; k < NK; ++k) {
    float w = w1[k];
    int idx = (int)(fbits(w) & 0xFFu);
    acc = fmaf(-w, vtb[idx * Dd], acc);
  }
  float sq = acc * acc;
#pragma unroll
  for (int off = 32; off > 0; off >>= 1) sq += __shfl_xor(sq, off, 64);

  __shared__ float red[RPB_B];
  if (l == 0) red[wv] = sq;
  __syncthreads();
  if (t == 0) {
    float tot = 0.f;
#pragma unroll
    for (int i = 0; i < RPB_B; ++i) tot += red[i];
    partial[blockIdx.x] = tot;
  }
}

// Kernel C: single-block final reduction.
__global__ __launch_bounds__(1024) void reduce_kernel(
    const float* __restrict__ partial, float* __restrict__ out) {
  const int t = threadIdx.x, wv = t >> 6, l = t & 63;
  float s = 0.f;
  for (int i = t; i < NB_B; i += 1024) s += partial[i];
#pragma unroll
  for (int off = 32; off > 0; off >>= 1) s += __shfl_xor(s, off, 64);
  __shared__ float red[16];
  if (l == 0) red[wv] = s;
  __syncthreads();
  if (t == 0) {
    float tot = 0.f;
#pragma unroll
    for (int i = 0; i < 16; ++i) tot += red[i];
    out[0] = tot * INV_N;
  }
}

extern "C" void kernel_launch(void* const* d_in, const int* in_sizes, int n_in,
                              void* d_out, int out_size, void* d_ws,
                              size_t ws_size, hipStream_t stream) {
  const float* att_s = (const float*)d_in[0];
  const float* att_t = (const float*)d_in[1];
  const float* v_s = (const float*)d_in[2];
  const float* v_t = (const float*)d_in[3];
  float* out = (float*)d_out;

  float* wpk = (float*)d_ws;                       // 2*ROWS*NK floats = 12.1 MB
  float* partial = wpk + (size_t)2 * ROWS * NK;    // + NB_B floats

  select_kernel<<<2 * NBLK, BLK, 0, stream>>>(att_s, att_t, wpk);
  gather_kernel<<<NB_B, 1024, 0, stream>>>(v_s, v_t, wpk, partial);
  reduce_kernel<<<1, 1024, 0, stream>>>(partial, out);
}

// Round 3
// 355.728 us; speedup vs baseline: 1.0654x; 1.0558x over previous
//
#include <hip/hip_runtime.h>
#include <cstdint>
#include <cfloat>

// Problem constants (B=64, H=12, P=197, D=64)
#define NK 10
constexpr int Pp   = 197;
constexpr int Dd   = 64;
constexpr int BH   = 64 * 12;            // 768 (b,h) groups
constexpr int ROWS = BH * Pp;            // 151296
constexpr int BLK  = 128;                // 2 independent waves per block
constexpr int WPB  = BLK / 64;           // 2 waves/block
constexpr int RPW  = 64;                 // rows per wave
constexpr int RPB  = RPW * WPB;          // 128 rows per block
constexpr int NBLK = ROWS / RPB;         // 1182 (exact)
constexpr int CH   = 32;                 // staging chunk width (cols)
constexpr int NFULL = Pp / CH;           // 6
constexpr int TAIL  = Pp - NFULL * CH;   // 5
constexpr float INV_N = 1.0f / 9682944.0f;   // 1/(ROWS*D)

constexpr int GBLK = 1024;               // gather block threads (16 waves)
constexpr int GW   = GBLK / 64;          // 16 waves

typedef float f32x4 __attribute__((ext_vector_type(4)));  // nontemporal-OK

__device__ __forceinline__ uint32_t fbits(float x) { return __float_as_uint(x); }
__device__ __forceinline__ float    bfl(uint32_t u) { return __uint_as_float(u); }

// Branchless sorted-insert into ascending a[0..9].
template <int CW>
__device__ __forceinline__ void consume_chunk(const float* __restrict__ trow,
                                              float a[NK]) {
#pragma unroll
  for (int j = 0; j < CW; ++j) {
    float x = trow[j];
#pragma unroll
    for (int s = 0; s < NK - 1; ++s) a[s] = fmaxf(a[s], fminf(x, a[s + 1]));
    a[NK - 1] = fmaxf(a[NK - 1], x);
  }
}

// Per-wave: RAW loads of chunk c into registers. No packing here — pure
// loads with no dependent VALU lets the compiler issue all 32 back-to-back
// (full memory-level parallelism) and defer the vmcnt waits to the store
// site, one consume-phase (~1200 cycles) later.
__device__ __forceinline__ void load_chunk_regs(const float* __restrict__ slab,
                                                int c, int l, float pf[CH]) {
  if (c < NFULL) {
    const int r0 = l >> 5, j = l & 31;
    const float* p = slab + c * CH + r0 * Pp + j;
#pragma unroll
    for (int i = 0; i < CH; ++i)
      pf[i] = __builtin_nontemporal_load(&p[i * 2 * Pp]);  // att is read-once
  } else {
    const float* cbase = slab + NFULL * CH;
#pragma unroll
    for (int i = 0; i < TAIL; ++i) {
      int e = l + i * 64;                  // 0..319 over 64 rows x 5 cols
      pf[i] = __builtin_nontemporal_load(&cbase[(e / TAIL) * Pp + (e % TAIL)]);
    }
  }
}

// Per-wave store into this wave's private [64][33] tile. Packing of the
// column index into the low 8 mantissa bits happens HERE (rel. perturbation
// 2^-16 — negligible for a scalar mean), after load latency has elapsed.
__device__ __forceinline__ void store_chunk(float (*twv)[CH + 1], int c, int l,
                                            const float pf[CH]) {
  if (c < NFULL) {
    const int r0 = l >> 5, j = l & 31;
    const uint32_t col = (uint32_t)(c * CH + j);
#pragma unroll
    for (int i = 0; i < CH; ++i)
      twv[r0 + 2 * i][j] = bfl((fbits(pf[i]) & 0xFFFFFF00u) | col);
  } else {
#pragma unroll
    for (int i = 0; i < TAIL; ++i) {
      int e = l + i * 64;
      uint32_t col = (uint32_t)(NFULL * CH + e % TAIL);
      twv[e / TAIL][e % TAIL] = bfl((fbits(pf[i]) & 0xFFFFFF00u) | col);
    }
  }
}

// Kernel A: wave-autonomous selection, zero barriers, 1-deep chunk pipeline.
__global__ __launch_bounds__(BLK, 4) void select_kernel(
    const float* __restrict__ att_s, const float* __restrict__ att_t,
    float* __restrict__ wpk /* [2][ROWS][NK] */) {
  __shared__ float tile[WPB][RPW][CH + 1];  // 16896 B

  const int t = threadIdx.x;
  const int wv = t >> 6, l = t & 63;
  const int bi = blockIdx.x;
  const int tensor = (bi >= NBLK) ? 1 : 0;
  const int slab = bi - tensor * NBLK;
  const float* A = tensor ? att_t : att_s;
  const int rowbase = slab * RPB + wv * RPW;

  float a[NK];
#pragma unroll
  for (int k = 0; k < NK; ++k) a[k] = -FLT_MAX;

  const float* slabp = A + (size_t)rowbase * Pp;
  float (*twv)[CH + 1] = tile[wv];
  float pf[CH];

  load_chunk_regs(slabp, 0, l, pf);
  for (int c = 0; c <= NFULL; ++c) {
    store_chunk(twv, c, l, pf);            // waits on chunk-c loads only
    if (c < NFULL) {
      load_chunk_regs(slabp, c + 1, l, pf);  // next chunk in flight
      consume_chunk<CH>(twv[l], a);          // hides the load latency
    } else {
      consume_chunk<TAIL>(twv[l], a);
    }
  }

  // softmax over the top-10 (full-row Z cancels against the renorm)
  float mx = a[NK - 1];
  float e[NK], s = 0.f;
#pragma unroll
  for (int k = 0; k < NK; ++k) { e[k] = __expf(a[k] - mx); s += e[k]; }
  float inv = 1.0f / s;

  // stage packed weights in the (now free) wave tile, then coalesced store
  float* flat = &twv[0][0];
#pragma unroll
  for (int k = 0; k < NK; ++k) {
    float w = e[k] * inv;  // w >= ~1e-6 -> normal, mantissa packing safe
    flat[l * NK + k] = bfl((fbits(w) & 0xFFFFFF00u) | (fbits(a[k]) & 0xFFu));
  }
  float* dst = wpk + ((size_t)tensor * ROWS + rowbase) * NK;
#pragma unroll
  for (int i = 0; i < NK; ++i) dst[l + i * 64] = flat[l + i * 64];
}

// Kernel B: one block per (b,h). Stage BOTH v slabs (2 x 197 x 64 floats =
// 100864 B) in LDS once, then all 197 rows gather from LDS. Cuts the
// gathered-v HBM traffic from ~775 MB (10x redundancy, cross-XCD) to the
// 77 MB read-once floor. LDS gather: lane l -> bank l%32, conflict-free.
__global__ __launch_bounds__(GBLK) void gather_kernel(
    const float* __restrict__ v_s, const float* __restrict__ v_t,
    const float* __restrict__ wpk, float* __restrict__ partial) {
  __shared__ float ls[2][Pp][Dd];   // 100864 B (gfx950: 160 KiB LDS/CU)
  __shared__ float red[GW];

  const int t = threadIdx.x, wv = t >> 6, l = t & 63;
  const int b = blockIdx.x;

  // stage both v slabs (float4-aligned: Pp*Dd*4 = 50432 B, multiple of 16)
  constexpr int NV4 = Pp * Dd / 4;  // 3152
  const f32x4* s4 = (const f32x4*)(v_s + (size_t)b * (Pp * Dd));
  const f32x4* t4 = (const f32x4*)(v_t + (size_t)b * (Pp * Dd));
  f32x4* d0 = (f32x4*)&ls[0][0][0];
  f32x4* d1 = (f32x4*)&ls[1][0][0];
  for (int i = t; i < NV4; i += GBLK) {
    d0[i] = __builtin_nontemporal_load(&s4[i]);
    d1[i] = __builtin_nontemporal_load(&t4[i]);
  }
  __syncthreads();

  const float* lsS = &ls[0][0][0];
  const float* lsT = &ls[1][0][0];

  float wsum = 0.f;
  for (int r = wv; r < Pp; r += GW) {          // wave-uniform rows
    const float* w0 = wpk + (size_t)(b * Pp + r) * NK;            // s_loads
    const float* w1 = wpk + ((size_t)ROWS + b * Pp + r) * NK;
    float acc = 0.f;
#pragma unroll
    for (int k = 0; k < NK; ++k) {
      float w = w0[k];
      int idx = (int)(fbits(w) & 0xFFu);
      acc = fmaf(w, lsS[idx * Dd + l], acc);
    }
#pragma unroll
    for (int k = 0; k < NK; ++k) {
      float w = w1[k];
      int idx = (int)(fbits(w) & 0xFFu);
      acc = fmaf(-w, lsT[idx * Dd + l], acc);
    }
    float sq = acc * acc;
#pragma unroll
    for (int off = 32; off > 0; off >>= 1) sq += __shfl_xor(sq, off, 64);
    wsum += sq;                                // replicated across lanes
  }

  if (l == 0) red[wv] = wsum;
  __syncthreads();
  if (t == 0) {
    float tot = 0.f;
#pragma unroll
    for (int i = 0; i < GW; ++i) tot += red[i];
    partial[b] = tot;
  }
}

// Kernel C: single-block final reduction over BH partials.
__global__ __launch_bounds__(1024) void reduce_kernel(
    const float* __restrict__ partial, float* __restrict__ out) {
  const int t = threadIdx.x, wv = t >> 6, l = t & 63;
  float s = 0.f;
  for (int i = t; i < BH; i += 1024) s += partial[i];
#pragma unroll
  for (int off = 32; off > 0; off >>= 1) s += __shfl_xor(s, off, 64);
  __shared__ float red[16];
  if (l == 0) red[wv] = s;
  __syncthreads();
  if (t == 0) {
    float tot = 0.f;
#pragma unroll
    for (int i = 0; i < 16; ++i) tot += red[i];
    out[0] = tot * INV_N;
  }
}

extern "C" void kernel_launch(void* const* d_in, const int* in_sizes, int n_in,
                              void* d_out, int out_size, void* d_ws,
                              size_t ws_size, hipStream_t stream) {
  const float* att_s = (const float*)d_in[0];
  const float* att_t = (const float*)d_in[1];
  const float* v_s = (const float*)d_in[2];
  const float* v_t = (const float*)d_in[3];
  float* out = (float*)d_out;

  float* wpk = (float*)d_ws;                       // 2*ROWS*NK floats = 12.1 MB
  float* partial = wpk + (size_t)2 * ROWS * NK;    // + BH floats

  select_kernel<<<2 * NBLK, BLK, 0, stream>>>(att_s, att_t, wpk);
  gather_kernel<<<BH, GBLK, 0, stream>>>(v_s, v_t, wpk, partial);
  reduce_kernel<<<1, 1024, 0, stream>>>(partial, out);
}